// Round 8
// baseline (179.431 us; speedup 1.0000x reference)
//
#include <hip/hip_runtime.h>
#include <hip/hip_fp16.h>

#define VIEWS 16
#define NN 256
#define DWS 131                     // dwords per LDS row (262 halves: cols -2..259)
#define ROWS 259                    // rows y=-1..257 (index = y+1)
#define LDS_DW (ROWS*DWS)           // 33,929 dwords = 135,716 B

typedef __fp16 h2 __attribute__((ext_vector_type(2)));
union U32H2 { uint32_t u; h2 h; };

template<int CTRL>
__device__ __forceinline__ float dpp_add(float x) {
    int t = __builtin_amdgcn_update_dpp(0, __float_as_int(x), CTRL, 0xF, 0xF, true);
    return x + __int_as_float(t);
}

__device__ __forceinline__ float fract_f(float x) {
#if __has_builtin(__builtin_amdgcn_fractf)
    return __builtin_amdgcn_fractf(x);
#else
    return x - floorf(x);
#endif
}

// one march-step: 4 taps (r=0..3), accumulate per-lane sums into acc[], and
// produce the 4-tap partial for the cross-lane reduction
#define DO_STEP(PARTIAL) do {                                                  \
    PARTIAL = 0.f;                                                             \
    _Pragma("unroll")                                                          \
    for (int r = 0; r < 4; ++r) {                                              \
        float u = fmaf(cu, tf, bu[r]);                                         \
        float v = fmaf(cv, tf, bv[r]);                                         \
        u = fminf(fmaxf(u, 1.0f), 258.0f);   /* -> v_med3 */                   \
        v = fminf(fmaxf(v, 0.0f), 257.0f);                                     \
        int x0 = (int)u;                                                       \
        int y0 = (int)v;                                                       \
        float wx = fract_f(u);                                                 \
        float wy = fract_f(v);                                                 \
        h2 wxp = __builtin_amdgcn_cvt_pkrtz(1.0f - wx, wx);                    \
        int d = (y0 << 7) + (y0 << 1) + y0 + (x0 >> 1);  /* y0*131 + x0/2 */   \
        uint32_t rA0 = lds[d];                                                 \
        uint32_t rA1 = lds[d + 1];                                             \
        uint32_t rB0 = lds[d + DWS];                                           \
        uint32_t rB1 = lds[d + DWS + 1];                                       \
        uint32_t sh = (uint32_t)(x0 << 4);   /* alignbit uses bits[4:0] */     \
        U32H2 pa, pb;                                                          \
        pa.u = __builtin_amdgcn_alignbit(rA1, rA0, sh);                        \
        pb.u = __builtin_amdgcn_alignbit(rB1, rB0, sh);                        \
        float a1 = __builtin_amdgcn_fdot2(wxp, pa.h, 0.0f, false);             \
        float a2 = __builtin_amdgcn_fdot2(wxp, pb.h, 0.0f, false);             \
        float t = fmaf(wy, a2 - a1, a1);                                       \
        acc[r] += t;                                                           \
        PARTIAL += t;                                                          \
    }                                                                          \
    tf += 1.0f;                                                                \
} while (0)

#define BUTTERFLY(P) do {                                                      \
    P = dpp_add<0xB1>(P);    /* xor 1  */                                      \
    P = dpp_add<0x4E>(P);    /* xor 2  */                                      \
    P = dpp_add<0x141>(P);   /* row_half_mirror */                             \
    P = dpp_add<0x140>(P);   /* row_mirror */                                  \
    P = dpp_add<0x142>(P);   /* row_bcast15 */                                 \
    P = dpp_add<0x143>(P);   /* row_bcast31: lane63 = total */                 \
} while (0)

__launch_bounds__(1024, 1)
__global__ void fp_kernel(const float* __restrict__ vol, float* __restrict__ out) {
    __shared__ uint32_t lds[LDS_DW];
    const int tid = threadIdx.x;
    const int z = blockIdx.x;

    // ---- zero LDS (borders must be 0) ----
    for (int i = tid; i < LDS_DW; i += 1024) lds[i] = 0u;
    __syncthreads();

    // ---- stage slice z as fp16 (dword = 2 adjacent-x halves) ----
    __half* ldsH = (__half*)lds;
    const float* sp = vol + (size_t)z * (NN * NN);
    #pragma unroll
    for (int i = 0; i < 16; ++i) {
        int e = i * 4096 + tid * 4;
        float4 v4 = *(const float4*)(sp + e);
        int row = (e >> 8) + 1;
        int col = (e & 255) + 2;               // even -> dword-aligned
        __half2* p = (__half2*)&ldsH[row * (2 * DWS) + col];
        p[0] = __halves2half2(__float2half_rn(v4.x), __float2half_rn(v4.y));
        p[1] = __halves2half2(__float2half_rn(v4.z), __float2half_rn(v4.w));
    }
    __syncthreads();

    // ---- 90-degree view pairing: wave -> (pair k, march-half h) ----
    // field S_k(x,y): bilinear sample of view k at (step x, ray y)
    //   proj_k[y]   = sum over x of S_k(x,y)       (row sums)
    //   proj_k8[y]  = sum over y of S_k(255-y, y') (column sums, 90° identity)
    // Mapping A: lane owns ray y, march over x. Row sums in registers,
    //            column sums via per-step butterfly.
    // Mapping B: lane owns column x, march over y. Column sums in registers,
    //            row sums via per-step butterfly.
    // Per-view choice kills LDS bank resonances: sigma_A = 131c - s/2 mod 32
    // is ~0 for k=1, ~-8 for k=2, ~16 for k=6 -> those use B (sigma_B = 131s + c/2).
    const int wave = tid >> 6;
    const int lane = tid & 63;
    const int k = wave >> 1;
    const int h = wave & 1;
    const bool mapB = (k == 1) || (k == 2) || (k == 6);
    const float ang = 0.017453292519943295f + (float)k * 0.19634954084936207f;
    const float c = cosf(ang), s = sinf(ang);

    // shifted coords: u = ix + 2 in [1,258], v = iy + 1 in [0,257]
    // u = c*(x+.5) - s*(y+.5) + 128(1-c+s) + 1.5
    // v = s*(x+.5) + c*(y+.5) + 128(1-s-c) + 0.5
    const float cu = mapB ? -s : c;        // du/dstep
    const float cv = mapB ?  c : s;        // dv/dstep
    const float pu = mapB ?  c : -s;       // du/dlane-coord
    const float pv = mapB ?  s :  c;       // dv/dlane-coord
    const float Cu = 128.0f * (1.0f - c + s) + 1.5f + 0.5f * (mapB ? -s : c);
    const float Cv = 128.0f * (1.0f - s - c) + 0.5f + 0.5f * (mapB ?  c : s);

    float bu[4], bv[4], acc[4];
    #pragma unroll
    for (int r = 0; r < 4; ++r) {
        float p = (float)(lane + 64 * r) + 0.5f;
        bu[r] = pu * p + Cu;
        bv[r] = pv * p + Cv;
        acc[r] = 0.0f;
    }
    float tf = (float)(128 * h);   // march variable (x in A, y in B)

    float creg0 = 0.0f, creg1 = 0.0f;   // butterfly捕 captures: steps 128h+lane, 128h+64+lane
    #pragma unroll 2
    for (int i = 0; i < 64; ++i) {
        float partial; DO_STEP(partial);
        BUTTERFLY(partial);
        float tot = __int_as_float(__builtin_amdgcn_readlane(__float_as_int(partial), 63));
        creg0 = (lane == i) ? tot : creg0;
    }
    #pragma unroll 2
    for (int i = 0; i < 64; ++i) {
        float partial; DO_STEP(partial);
        BUTTERFLY(partial);
        float tot = __int_as_float(__builtin_amdgcn_readlane(__float_as_int(partial), 63));
        creg1 = (lane == i) ? tot : creg1;
    }

    __syncthreads();   // all taps done; safe to reuse LDS

    // ---- assemble [256 y][16 views] in LDS ----
    float* lout = (float*)lds;   // 4096 floats
    // phase 1: exclusive writes (disjoint y-ranges across h) + h==0 shared writes
    if (!mapB) {
        // butterfly results = column sums at x = 128h+i -> view k+8 at y = 255-x
        int ybase = 255 - 128 * h;
        lout[(ybase - lane) * VIEWS + (k + 8)] = creg0;
        lout[(ybase - 64 - lane) * VIEWS + (k + 8)] = creg1;
    } else {
        // butterfly results = row sums at y = 128h+i -> view k
        int ybase = 128 * h;
        lout[(ybase + lane) * VIEWS + k] = creg0;
        lout[(ybase + 64 + lane) * VIEWS + k] = creg1;
    }
    if (h == 0) {
        #pragma unroll
        for (int r = 0; r < 4; ++r) {
            int y = mapB ? (255 - lane - 64 * r) : (lane + 64 * r);
            int vt = mapB ? (k + 8) : k;
            lout[y * VIEWS + vt] = acc[r];
        }
    }
    __syncthreads();
    if (h == 1) {
        #pragma unroll
        for (int r = 0; r < 4; ++r) {
            int y = mapB ? (255 - lane - 64 * r) : (lane + 64 * r);
            int vt = mapB ? (k + 8) : k;
            lout[y * VIEWS + vt] += acc[r];
        }
    }
    __syncthreads();

    float4 v4 = *(float4*)&lout[tid * 4];
    float4* o4 = (float4*)(out + (size_t)z * (NN * VIEWS));
    o4[tid] = v4;
}

extern "C" void kernel_launch(void* const* d_in, const int* in_sizes, int n_in,
                              void* d_out, int out_size, void* d_ws, size_t ws_size,
                              hipStream_t stream) {
    const float* vol = (const float*)d_in[0];
    float* out = (float*)d_out;
    fp_kernel<<<NN, 1024, 0, stream>>>(vol, out);
}